// Round 14
// baseline (650.781 us; speedup 1.0000x reference)
//
#include <hip/hip_runtime.h>
#include <math.h>

#define H 200
constexpr float INV_PI = 0.31830988618379067f;

typedef __attribute__((ext_vector_type(8))) short bf16x8;
typedef __attribute__((ext_vector_type(4))) float f32x4;
typedef __attribute__((ext_vector_type(4))) short s16x4;

__device__ __forceinline__ short f2bf(float f) {
  unsigned u = __float_as_uint(f);
  u += 0x7FFF + ((u >> 16) & 1);  // RNE
  return (short)(u >> 16);
}
__device__ __forceinline__ float bf2f(short s) {
  return __uint_as_float(((unsigned)(unsigned short)s) << 16);
}
__device__ __forceinline__ float angsim(float c) {
  c = fminf(fmaxf(c * 0.99999f, -1.f), 1.f);
  return 1.f - acosf(c) * INV_PI;
}
__device__ __forceinline__ const float* sel_mod(int m, const float* xa, const float* xv,
                                                const float* xt) {
  return (m == 0) ? xa : ((m == 1) ? xv : xt);
}

// ---- 16x16 per-wave MFMA core: direct global, K = NK*32 ----
template <int NK>
__device__ __forceinline__ void gemm1(const short* __restrict__ A, int lda,
                                      const short* __restrict__ B, int ldb, f32x4& acc) {
  const int l = threadIdx.x & 63;
  const short* ap = A + (l & 15) * lda + (l >> 4) * 8;
  const short* bp = B + (l & 15) * ldb + (l >> 4) * 8;
  #pragma unroll
  for (int t = 0; t < NK; t++) {
    bf16x8 a = *(const bf16x8*)(ap + t * 32);
    bf16x8 b = *(const bf16x8*)(bp + t * 32);
    acc = __builtin_amdgcn_mfma_f32_16x16x32_bf16(a, b, acc, 0, 0, 0);
  }
}

// ---- 16x64 per-wave core (intra Gram) ----
template <int NK>
__device__ __forceinline__ void gemm4(const short* __restrict__ A, int lda,
                                      const short* __restrict__ B, int ldb, f32x4 acc[4]) {
  const int l = threadIdx.x & 63;
  const short* ap = A + (l & 15) * lda + (l >> 4) * 8;
  const short* bp = B + (l & 15) * ldb + (l >> 4) * 8;
  const int o16 = 16 * ldb, o32 = 32 * ldb, o48 = 48 * ldb;
  #pragma unroll
  for (int t = 0; t < NK; t++) {
    bf16x8 a = *(const bf16x8*)(ap + t * 32);
    bf16x8 b0 = *(const bf16x8*)(bp + t * 32);
    bf16x8 b1 = *(const bf16x8*)(bp + o16 + t * 32);
    bf16x8 b2 = *(const bf16x8*)(bp + o32 + t * 32);
    bf16x8 b3 = *(const bf16x8*)(bp + o48 + t * 32);
    acc[0] = __builtin_amdgcn_mfma_f32_16x16x32_bf16(a, b0, acc[0], 0, 0, 0);
    acc[1] = __builtin_amdgcn_mfma_f32_16x16x32_bf16(a, b1, acc[1], 0, 0, 0);
    acc[2] = __builtin_amdgcn_mfma_f32_16x16x32_bf16(a, b2, acc[2], 0, 0, 0);
    acc[3] = __builtin_amdgcn_mfma_f32_16x16x32_bf16(a, b3, acc[3], 0, 0, 0);
  }
}

// ================= prep kernel (one-shot, known-good) =================
__global__ __launch_bounds__(256) void prep_k(
    const float* __restrict__ xa, const float* __restrict__ xv, const float* __restrict__ xt,
    const float* __restrict__ fc0_w, const float* __restrict__ conv_w,
    const float* __restrict__ tm_w, const float* __restrict__ cross_w,
    short* __restrict__ fc0_wt, short* __restrict__ conv_wt, short* __restrict__ tm_wt,
    short* __restrict__ cross_wt, short* __restrict__ bigA, short* __restrict__ tmA,
    short* __restrict__ convA, short* __restrict__ convA2, short* __restrict__ hxb,
    short* __restrict__ prodb, float* __restrict__ inv_norm, float* __restrict__ cw,
    float* __restrict__ out) {
  __shared__ float tile[64][65];
  const int bx = blockIdx.x;
  const int lane = threadIdx.x & 63;
  const int wrp = threadIdx.x >> 6;

  if (bx < 444) {  // weight transpose tiles (coalesced both sides)
    const float* src; short* dst; int srcK, KP, kt, ct;
    if (bx < 16) {
      src = fc0_w; dst = fc0_wt; srcK = 200; KP = 224; kt = bx >> 2; ct = bx & 3;
    } else if (bx < 156) {
      int b = (bx - 16) / 28, rem = (bx - 16) % 28;
      kt = rem >> 2; ct = rem & 3; srcK = 400; KP = 416;
      if (b < 2) { src = conv_w + b * 80000; dst = conv_wt + b * 86528; }
      else { src = tm_w + (b - 2) * 80000; dst = tm_wt + (b - 2) * 86528; }
    } else {
      int q = bx - 156, pp = q >> 4, rem = q & 15;
      kt = rem >> 2; ct = rem & 3; srcK = 200; KP = 224;
      src = cross_w + (pp / 3) * 120000 + (pp % 3) * 40000;
      dst = cross_wt + pp * (208 * 224);
    }
    const int k0 = kt * 64, c0 = ct * 64;
    #pragma unroll 4
    for (int r = 0; r < 16; r++) {
      int ky = r * 4 + wrp, k = k0 + ky, c = c0 + lane;
      tile[ky][lane] = (k < srcK && c < 200) ? src[k * 200 + c] : 0.f;
    }
    __syncthreads();
    #pragma unroll 4
    for (int r = 0; r < 16; r++) {
      int cy = r * 4 + wrp, c = c0 + cy, k = k0 + lane;
      if (c < 208 && k < KP) dst[c * KP + k] = f2bf(tile[lane][cy]);
    }
  } else if (bx < 1980) {  // per-node pack + norm + pads
    int u = (bx - 444) * 4 + wrp, m = u >> 11, a = u & 2047;
    const float* p = sel_mod(m, xa, xv, xt) + a * H;
    float v0 = p[lane], v1 = p[lane + 64], v2 = p[lane + 128];
    float v3 = (lane < 8) ? p[lane + 192] : 0.f;
    float s = v0 * v0 + v1 * v1 + v2 * v2 + v3 * v3;
    #pragma unroll
    for (int off = 32; off; off >>= 1) s += __shfl_down(s, off, 64);
    if (lane == 0) inv_norm[u] = 1.f / sqrtf(s);
    short b0 = f2bf(v0), b1 = f2bf(v1), b2 = f2bf(v2), b3 = f2bf(v3);
    short* br = bigA + u * 224;
    br[lane] = b0; br[lane + 64] = b1; br[lane + 128] = b2;
    if (lane < 32) br[192 + lane] = (lane < 8) ? b3 : (short)0;
    short* tr = tmA + u * 416;
    tr[lane] = b0; tr[lane + 64] = b1; tr[lane + 128] = b2;
    if (lane < 8) tr[192 + lane] = b3;
    if (lane < 16) {
      tr[400 + lane] = 0;
      convA[u * 416 + 400 + lane] = 0;
      convA2[u * 416 + 400 + lane] = 0;
    }
    if (lane < 24) {
      hxb[u * 224 + 200 + lane] = 0;
      prodb[u * 224 + 200 + lane] = 0;
    }
  } else if (bx < 2492) {  // cross-modal sims
    int a = (bx - 1980) * 4 + wrp;
    const float* pa = xa + a * H;
    const float* pv = xv + a * H;
    const float* pt = xt + a * H;
    float a0 = pa[lane], a1 = pa[lane + 64], a2 = pa[lane + 128],
          a3 = (lane < 8) ? pa[lane + 192] : 0.f;
    float q0 = pv[lane], q1 = pv[lane + 64], q2 = pv[lane + 128],
          q3 = (lane < 8) ? pv[lane + 192] : 0.f;
    float t0 = pt[lane], t1 = pt[lane + 64], t2 = pt[lane + 128],
          t3 = (lane < 8) ? pt[lane + 192] : 0.f;
    float red[6];
    red[0] = a0 * a0 + a1 * a1 + a2 * a2 + a3 * a3;
    red[1] = q0 * q0 + q1 * q1 + q2 * q2 + q3 * q3;
    red[2] = t0 * t0 + t1 * t1 + t2 * t2 + t3 * t3;
    red[3] = a0 * q0 + a1 * q1 + a2 * q2 + a3 * q3;
    red[4] = a0 * t0 + a1 * t1 + a2 * t2 + a3 * t3;
    red[5] = q0 * t0 + q1 * t1 + q2 * t2 + q3 * t3;
    #pragma unroll
    for (int off = 32; off; off >>= 1)
      #pragma unroll
      for (int q = 0; q < 6; q++) red[q] += __shfl_down(red[q], off, 64);
    if (lane == 0) {
      float ia = 1.f / sqrtf(red[0]), iv = 1.f / sqrtf(red[1]), it = 1.f / sqrtf(red[2]);
      cw[a] = angsim(red[3] * ia * iv);
      cw[2048 + a] = angsim(red[4] * ia * it);
      cw[4096 + a] = angsim(red[5] * iv * it);
    }
  } else {  // zero d_out (2048*6)
    int i = (bx - 2492) * 1024 + threadIdx.x * 4;
    *(f32x4*)(out + i) = f32x4{0.f, 0.f, 0.f, 0.f};
  }
}

// ========== per-dialogue pipeline: 32 blocks x 1024 threads, only __syncthreads ==========
__global__ __launch_bounds__(1024, 4) void dlg1_k(
    const float* __restrict__ fc0_b, const float* __restrict__ tm_b,
    const float* __restrict__ cross_b, const float* __restrict__ uniw,
    const float* __restrict__ unib,
    const short* __restrict__ fc0_wt, const short* __restrict__ conv_wt,
    const short* __restrict__ tm_wt, const short* __restrict__ cross_wt,
    const short* __restrict__ bigA, short* __restrict__ convA, short* __restrict__ convA2,
    short* __restrict__ tmA, short* __restrict__ hxb, short* __restrict__ h_t,
    short* __restrict__ intra_s, short* __restrict__ prodb,
    const float* __restrict__ inv_norm, const float* __restrict__ cw,
    float* __restrict__ out) {
  __shared__ float sdinv[192];
  const int b = blockIdx.x;  // dialogue 0..31
  const int lane = threadIdx.x & 63;
  const int wid = threadIdx.x >> 6;  // 0..15
  const int fr = lane & 15, fq = lane >> 4;
  const int jm_t[6] = {1, 2, 0, 2, 0, 1};
  const int pc_t[6] = {0, 1, 0, 2, 1, 2};

  // ===== Stage 1: intra Gram + dinv (12 waves: m 0..2 x row-tile 0..3) =====
  float ang[4][4];
  int g_m = wid >> 2, g_rt = wid & 3;
  int g_u0 = g_m * 2048 + b * 64;         // first node of (m, b)
  int g_iL0 = g_rt * 16 + fq * 4;         // local row in 0..63
  if (wid < 12) {
    f32x4 acc4[4] = {};
    gemm4<7>(bigA + (g_u0 + g_rt * 16) * 224, 224, bigA + g_u0 * 224, 224, acc4);
    float rsum[4] = {0.f, 0.f, 0.f, 0.f};
    #pragma unroll
    for (int j = 0; j < 4; j++) {
      float invj = inv_norm[g_u0 + j * 16 + fr];
      #pragma unroll
      for (int r = 0; r < 4; r++) {
        float av = angsim(acc4[j][r] * inv_norm[g_u0 + g_iL0 + r] * invj);
        ang[j][r] = av;
        rsum[r] += av;
      }
    }
    #pragma unroll
    for (int mask = 1; mask < 16; mask <<= 1)
      #pragma unroll
      for (int r = 0; r < 4; r++) rsum[r] += __shfl_xor(rsum[r], mask, 64);
    if (fr == 0) {
      #pragma unroll
      for (int r = 0; r < 4; r++) {
        int a = b * 64 + g_iL0 + r;
        float c1 = (g_m <= 1) ? cw[a] : cw[2048 + a];
        float c2 = (g_m == 0) ? cw[2048 + a] : cw[4096 + a];
        sdinv[g_m * 64 + g_iL0 + r] = 1.f / sqrtf(rsum[r] + c1 + c2);
      }
    }
  }
  __syncthreads();
  if (wid < 12) {
    const int mb = g_m * 32 + b;
    #pragma unroll
    for (int j = 0; j < 4; j++) {
      int jn = j * 16 + fr;
      float dj = sdinv[g_m * 64 + jn];
      #pragma unroll
      for (int r = 0; r < 4; r++)
        intra_s[mb * 4096 + (g_iL0 + r) * 64 + jn] =
            f2bf(ang[j][r] * sdinv[g_m * 64 + g_iL0 + r] * dj);
    }
  }

  // ===== Stage 2: fc0 (156 tasks = 12 row-tiles x 13 c-tiles) =====
  #pragma unroll 1
  for (int t = wid; t < 156; t += 16) {
    int rt = t % 12, ct = t / 12;
    int m = rt >> 2, lt = rt & 3;
    int row0 = m * 2048 + b * 64 + lt * 16;
    int c0 = ct * 16;
    f32x4 acc = {};
    gemm1<7>(fc0_wt + c0 * 224, 224, bigA + row0 * 224, 224, acc);
    int node = row0 + fr, cb = c0 + fq * 4;
    if (cb < 200) {
      s16x4 oh;
      #pragma unroll
      for (int r = 0; r < 4; r++) {
        float v = fmaxf(acc[r] + fc0_b[cb + r], 0.f);
        oh[r] = f2bf(v);
        h_t[(cb + r) * 6144 + node] = oh[r];
      }
      *(s16x4*)(convA + node * 416 + 200 + cb) = oh;
      *(s16x4*)(convA2 + node * 416 + 200 + cb) = oh;
    }
  }
  __syncthreads();

  // ===== GCNII layers =====
  #pragma unroll 1
  for (int layer = 0; layer < 2; layer++) {
    short* dst = (layer == 0) ? convA : convA2;
    // adj
    #pragma unroll 1
    for (int t = wid; t < 156; t += 16) {
      int rt = t % 12, ct = t / 12;
      int m = rt >> 2, ut = rt & 3;
      int c0 = ct * 16;
      int nb_ = m * 2048 + b * 64;
      f32x4 acc = {};
      gemm1<2>(h_t + c0 * 6144 + nb_, 6144, intra_s + (m * 32 + b) * 4096 + ut * 16 * 64,
               64, acc);
      int ll = ut * 16 + fr;           // local 0..63
      int u = nb_ + ll, cb = c0 + fq * 4;
      if (cb < 200) {
        int a = b * 64 + ll;
        int n1, n2, p1, p2;
        if (m == 0)      { n1 = 1; p1 = 0; n2 = 2; p2 = 1; }
        else if (m == 1) { n1 = 0; p1 = 0; n2 = 2; p2 = 2; }
        else             { n1 = 0; p1 = 1; n2 = 1; p2 = 2; }
        float dv = sdinv[m * 64 + ll];
        int o1 = n1 * 2048 + a, o2 = n2 * 2048 + a;
        float w1 = cw[p1 * 2048 + a] * dv * sdinv[n1 * 64 + ll];
        float w2 = cw[p2 * 2048 + a] * dv * sdinv[n2 * 64 + ll];
        s16x4 o;
        #pragma unroll
        for (int r = 0; r < 4; r++) {
          int c = cb + r;
          float v = acc[r] + w1 * bf2f(h_t[c * 6144 + o1]) + w2 * bf2f(h_t[c * 6144 + o2]);
          o[r] = f2bf(v);
        }
        *(s16x4*)(dst + u * 416 + cb) = o;
      }
    }
    __syncthreads();
    // conv
    const float beta = (layer == 0) ? 0.40546510810816444f : 0.22314355131420976f;
    const float ombeta = 1.f - beta;
    const short* Wt = conv_wt + layer * 86528;
    #pragma unroll 1
    for (int t = wid; t < 156; t += 16) {
      int rt = t % 12, ct = t / 12;
      int m = rt >> 2, lt = rt & 3;
      int row0 = m * 2048 + b * 64 + lt * 16;
      int c0 = ct * 16;
      f32x4 acc = {};
      gemm1<13>(Wt + c0 * 416, 416, dst + row0 * 416, 416, acc);
      int node = row0 + fr, cb = c0 + fq * 4;
      if (cb < 200) {
        s16x4 hiv = *(const s16x4*)(dst + node * 416 + cb);
        s16x4 h0v = *(const s16x4*)(dst + node * 416 + 200 + cb);
        if (layer == 0) {
          #pragma unroll
          for (int r = 0; r < 4; r++) {
            float rr = 0.9f * bf2f(hiv[r]) + 0.1f * bf2f(h0v[r]);
            h_t[(cb + r) * 6144 + node] = f2bf(fmaxf(beta * acc[r] + ombeta * rr, 0.f));
          }
        } else {
          s16x4 o;
          #pragma unroll
          for (int r = 0; r < 4; r++) {
            float rr = 0.9f * bf2f(hiv[r]) + 0.1f * bf2f(h0v[r]);
            o[r] = f2bf(fmaxf(beta * acc[r] + ombeta * rr, 0.f));
          }
          *(s16x4*)(tmA + node * 416 + 200 + cb) = o;
        }
      }
    }
    __syncthreads();
  }

  // ===== tm =====
  #pragma unroll 1
  for (int t = wid; t < 156; t += 16) {
    int rt = t % 12, ct = t / 12;
    int m = rt >> 2, lt = rt & 3;
    int row0 = m * 2048 + b * 64 + lt * 16;
    int c0 = ct * 16;
    f32x4 acc = {};
    gemm1<13>(tm_wt + m * 86528 + c0 * 416, 416, tmA + row0 * 416, 416, acc);
    int node = row0 + fr, cb = c0 + fq * 4;
    if (cb < 200) {
      s16x4 o;
      #pragma unroll
      for (int r = 0; r < 4; r++) o[r] = f2bf(fmaxf(acc[r] + tm_b[m * H + cb + r], 0.f));
      *(s16x4*)(hxb + node * 224 + cb) = o;
    }
  }
  __syncthreads();

  // ===== elementwise products =====
  {
    const int im_q[3] = {0, 0, 1}, jm_q[3] = {1, 2, 2};
    #pragma unroll 1
    for (int it = threadIdx.x; it < 9600; it += 1024) {  // 3 * 64 * 50 s16x4 groups
      int q = it / 3200, rem = it - q * 3200;
      int l = rem / 50, c = (rem - l * 50) * 4;
      int na = b * 64 + l;
      s16x4 aa = *(const s16x4*)(hxb + (im_q[q] * 2048 + na) * 224 + c);
      s16x4 bb = *(const s16x4*)(hxb + (jm_q[q] * 2048 + na) * 224 + c);
      s16x4 o;
      #pragma unroll
      for (int r = 0; r < 4; r++) o[r] = f2bf(bf2f(aa[r]) * bf2f(bb[r]));
      *(s16x4*)(prodb + (q * 2048 + na) * 224 + c) = o;
    }
  }
  __syncthreads();

  // ===== cross gate + fused final projection (312 tasks = 6p x 4ut x 13ct) =====
  #pragma unroll 1
  for (int t = wid; t < 312; t += 16) {
    int p = t / 52, rem = t - p * 52;
    int ut = rem / 13, ct = rem - ut * 13;
    int c0 = ct * 16;
    const int im = p >> 1, jm = jm_t[p];
    const short* Wp = cross_wt + p * (3 * 208 * 224);
    int urow = b * 64 + ut * 16;
    f32x4 acc = {};
    gemm1<7>(Wp + c0 * 224, 224, hxb + (im * 2048 + urow) * 224, 224, acc);
    gemm1<7>(Wp + 208 * 224 + c0 * 224, 224, hxb + (jm * 2048 + urow) * 224, 224, acc);
    gemm1<7>(Wp + 2 * 208 * 224 + c0 * 224, 224, prodb + (pc_t[p] * 2048 + urow) * 224,
             224, acc);
    int a = urow + fr, cb = c0 + fq * 4;
    float pt[6] = {0.f, 0.f, 0.f, 0.f, 0.f, 0.f};
    if (cb < 200) {
      s16x4 ai = *(const s16x4*)(hxb + (im * 2048 + a) * 224 + cb);
      s16x4 aj = *(const s16x4*)(hxb + (jm * 2048 + a) * 224 + cb);
      const float* Wu = uniw + im * (H * 6);
      #pragma unroll
      for (int r = 0; r < 4; r++) {
        float x = acc[r] + cross_b[p * H + cb + r];
        float z = 1.f / (1.f + expf(-x));
        float o = z * bf2f(ai[r]) + (1.f - z) * bf2f(aj[r]);
        #pragma unroll
        for (int tt = 0; tt < 6; tt++) pt[tt] += o * Wu[(cb + r) * 6 + tt];
      }
    }
    #pragma unroll
    for (int tt = 0; tt < 6; tt++) {
      pt[tt] += __shfl_xor(pt[tt], 16, 64);
      pt[tt] += __shfl_xor(pt[tt], 32, 64);
    }
    if (fq == 0) {
      if (p == 0 && ct == 0) {
        #pragma unroll
        for (int tt = 0; tt < 6; tt++) pt[tt] += unib[tt] + unib[6 + tt] + unib[12 + tt];
      }
      #pragma unroll
      for (int tt = 0; tt < 6; tt++) atomicAdd(out + a * 6 + tt, pt[tt]);
    }
  }
}

extern "C" void kernel_launch(void* const* d_in, const int* in_sizes, int n_in,
                              void* d_out, int out_size, void* d_ws, size_t ws_size,
                              hipStream_t stream) {
  const float* xa = (const float*)d_in[0];
  const float* xv = (const float*)d_in[1];
  const float* xt = (const float*)d_in[2];
  const float* fc0_w = (const float*)d_in[3];
  const float* fc0_b = (const float*)d_in[4];
  const float* conv_w = (const float*)d_in[5];
  const float* tm_w = (const float*)d_in[6];
  const float* tm_b = (const float*)d_in[7];
  const float* cross_w = (const float*)d_in[8];
  const float* cross_b = (const float*)d_in[9];
  const float* uni_w = (const float*)d_in[10];
  const float* uni_b = (const float*)d_in[11];
  float* out = (float*)d_out;
  float* ws = (float*)d_ws;

  float* inv_norm = ws;                        // 6144
  float* cw = ws + 6144;                       // 6144
  short* bigA = (short*)(ws + 12288);          // 6144*224 sh -> 700416
  short* convA = (short*)(ws + 700416);        // 6144*416 sh -> 1978368
  short* convA2 = (short*)(ws + 1978368);      // 6144*416 sh -> 3256320
  short* tmA = (short*)(ws + 3256320);         // 6144*416 sh -> 4534272
  short* hxb = (short*)(ws + 4534272);         // 6144*224 sh -> 5222400
  short* h_t = (short*)(ws + 5222400);         // 208*6144 sh -> 5861376
  short* intra_s = (short*)(ws + 5861376);     // 96*4096 sh -> 6057984
  short* fc0_wt = (short*)(ws + 6057984);      // 208*224 sh -> 6081280
  short* conv_wt = (short*)(ws + 6081280);     // 2*208*416 sh -> 6167808
  short* tm_wt = (short*)(ws + 6167808);       // 3*208*416 sh -> 6297600
  short* cross_wt = (short*)(ws + 6297600);    // 18*208*224 sh -> 6716928
  short* prodb = (short*)(ws + 6716928);       // 3*2048*224 sh -> 7405056

  prep_k<<<2504, 256, 0, stream>>>(xa, xv, xt, fc0_w, conv_w, tm_w, cross_w,
                                   fc0_wt, conv_wt, tm_wt, cross_wt,
                                   bigA, tmA, convA, convA2, hxb, prodb, inv_norm, cw, out);
  dlg1_k<<<32, 1024, 0, stream>>>(fc0_b, tm_b, cross_b, uni_w, uni_b,
                                  fc0_wt, conv_wt, tm_wt, cross_wt, bigA, convA, convA2,
                                  tmA, hxb, h_t, intra_s, prodb, inv_norm, cw, out);
}